// Round 5
// baseline (162.742 us; speedup 1.0000x reference)
//
#include <hip/hip_runtime.h>
#include <hip/hip_bf16.h>

#define IN_F   4096
#define OUT_F  4096
#define QBLK   8
#define NBLKS  512
#define NTOK   1024
#define NCENT  2048
#define SPLITK 4
#define BM     256
#define BN     128

typedef unsigned int u32;
typedef unsigned short u16;
typedef __attribute__((ext_vector_type(8))) short short8;   // 8 bf16 (MFMA A/B frag)
typedef __attribute__((ext_vector_type(4))) float floatx4;  // 16x16 MFMA C/D frag

// round-to-nearest-even fp32 -> bf16
__device__ __forceinline__ u16 f2bf(float f) {
  union { float f; u32 u; } v; v.f = f;
  u32 u = v.u;
  return (u16)((u + 0x7fffu + ((u >> 16) & 1u)) >> 16);
}

__device__ __forceinline__ void load_lds_16(const void* g, void* l) {
  __builtin_amdgcn_global_load_lds(
      (const __attribute__((address_space(1))) u32*)g,
      (__attribute__((address_space(3))) u32*)l, 16, 0, 0);
}

// ---------------------------------------------------------------------------
// Prep: cast x->bf16, cast centroids->bf16, init out = bias (for atomic GEMM).
// ---------------------------------------------------------------------------
__global__ __launch_bounds__(256) void prep_kernel(
    const float* __restrict__ x, const float* __restrict__ cent,
    const float* __restrict__ bias,
    u16* __restrict__ xb, u16* __restrict__ centb, float* __restrict__ out) {
  const int g = blockIdx.x * 256 + threadIdx.x;   // 0 .. 512K-1

  {
    const float4* xv = (const float4*)x;
    float4 a = xv[(size_t)g * 2];
    float4 b = xv[(size_t)g * 2 + 1];
    union { u16 s[8]; uint4 v; } o;
    o.s[0] = f2bf(a.x); o.s[1] = f2bf(a.y); o.s[2] = f2bf(a.z); o.s[3] = f2bf(a.w);
    o.s[4] = f2bf(b.x); o.s[5] = f2bf(b.y); o.s[6] = f2bf(b.z); o.s[7] = f2bf(b.w);
    ((uint4*)xb)[g] = o.v;
  }
  {
    const float4* b4 = (const float4*)bias;
    float4* o4 = (float4*)out;
    o4[(size_t)g * 2]     = b4[(2 * g) & 1023];
    o4[(size_t)g * 2 + 1] = b4[(2 * g + 1) & 1023];
  }
  if (g < NCENT) {
    const float4* cv = (const float4*)cent;
    float4 a = cv[(size_t)g * 2];
    float4 b = cv[(size_t)g * 2 + 1];
    union { u16 s[8]; uint4 v; } o;
    o.s[0] = f2bf(a.x); o.s[1] = f2bf(a.y); o.s[2] = f2bf(a.z); o.s[3] = f2bf(a.w);
    o.s[4] = f2bf(b.x); o.s[5] = f2bf(b.y); o.s[6] = f2bf(b.z); o.s[7] = f2bf(b.w);
    ((uint4*)centb)[g] = o.v;
  }
}

// ---------------------------------------------------------------------------
// Fused GEMM, fat-wave-tile edition.
// C[m][n] += sum_k x[m][k] * centroids[assign[(k/8)*OUT_F+n]][k%8]
// Block tile 256x128, 4 waves (2x2); wave tile 128x64 = 8x4 of 16x16x32 MFMA
// (32 independent accumulators -> deep MFMA pipelining, unlike the 32x32
// variant). LDS bytes/MAC = 0.0305 vs 0.078 for the 64x64 wave tile: this
// kernel was measured LDS-BW-bound, so fatter tiles are the direct lever.
// A: DMA-staged 16KB/kt, XOR swizzle (chunk ^ (row&3)) -> conflict-free reads.
// B: one 16B LDS gather per 16-col frag per 8-k quant block from the 32KB
//    bf16 centroid table; idx prefetched one kt ahead, issued before the
//    barrier so global latency merges into the DMA drain.
// Split-K=4 over gridDim.z; atomic accumulate into bias-pre-set out.
// ---------------------------------------------------------------------------
__global__ __launch_bounds__(256, 2) void gemm_fused4_kernel(
    const u16* __restrict__ A,      // xb [NTOK][IN_F] bf16
    const u16* __restrict__ centb,  // [NCENT][8] bf16
    const int* __restrict__ assign, // [NBLKS*OUT_F] block-major
    float* __restrict__ out) {      // [NTOK][OUT_F], pre-initialized to bias
  __shared__ __align__(16) u16 cs[NCENT * 8];   // 32 KB
  __shared__ __align__(16) u16 As[BM * 32];     // 16 KB
  const int NKT = (IN_F / SPLITK) / 32;         // 32 kt iterations

  const int t = threadIdx.x;
  const int lane = t & 63;
  const int wv = t >> 6;
  const int wm = wv >> 1;          // m offset wm*128
  const int wn = wv & 1;           // n offset wn*64
  const int quad = lane >> 4;
  const int r16 = lane & 15;
  const int m0 = blockIdx.y * BM;
  const int n0 = blockIdx.x * BN;
  const int k_base = blockIdx.z * (IN_F / SPLITK);

  // stage centroid table: 2048 x 16B chunks, 8 per thread (DMA)
#pragma unroll
  for (int it = 0; it < 8; ++it) {
    int c = it * 256 + t;
    load_lds_16(centb + (size_t)c * 8, cs + (size_t)c * 8);
  }

  floatx4 acc[8][4];
#pragma unroll
  for (int i = 0; i < 8; ++i)
#pragma unroll
    for (int j = 0; j < 4; ++j)
#pragma unroll
      for (int r = 0; r < 4; ++r) acc[i][j][r] = 0.0f;

  // idx: entry (kt, j) = ip[kt*4*OUT_F + j*16]; kb row = k_base/8 + kt*4 + quad
  const int* ip = assign + (size_t)((k_base >> 3) + quad) * OUT_F + n0 + wn * 64 + r16;

  // A staging: 1024 chunks of 16B, 4 per thread; chunk p -> row p>>2,
  // global-side swizzled chunk (p&3)^(row&3)
  const u16* ag[4];
#pragma unroll
  for (int i = 0; i < 4; ++i) {
    int p = i * 256 + t;
    int row = p >> 2;
    ag[i] = A + (size_t)(m0 + row) * IN_F + k_base + (((p & 3) ^ (row & 3)) * 8);
  }
  const int sq = quad ^ (r16 & 3);   // read-side swizzle

  // prefetch idx for kt=0
  int id[4];
#pragma unroll
  for (int j = 0; j < 4; ++j) id[j] = ip[j * 16];

  const short8* csv = (const short8*)cs;
  const short8* Asv = (const short8*)As;

  for (int kt = 0; kt < NKT; ++kt) {
    // stage A tile for this kt (4 DMA chunks per thread)
#pragma unroll
    for (int i = 0; i < 4; ++i)
      load_lds_16(ag[i] + kt * 32, &As[(i * 256 + t) * 8]);

    // prefetch idx for kt+1 BEFORE the barrier: its latency overlaps the
    // DMA drain the barrier performs (clamped re-read on last iter)
    const int ktn = (kt + 1 < NKT) ? (kt + 1) : kt;
    int nid[4];
#pragma unroll
    for (int j = 0; j < 4; ++j)
      nid[j] = ip[(size_t)(ktn * 4) * OUT_F + j * 16];

    __syncthreads();   // drains DMA (incl. cs on kt=0) and idx loads

    short8 bfr[4];
#pragma unroll
    for (int j = 0; j < 4; ++j) bfr[j] = csv[id[j]];
    short8 af[8];
#pragma unroll
    for (int i = 0; i < 8; ++i)
      af[i] = Asv[(wm * 128 + i * 16 + r16) * 4 + sq];

#pragma unroll
    for (int i = 0; i < 8; ++i)
#pragma unroll
      for (int j = 0; j < 4; ++j)
        acc[i][j] = __builtin_amdgcn_mfma_f32_16x16x32_bf16(af[i], bfr[j], acc[i][j], 0, 0, 0);

#pragma unroll
    for (int j = 0; j < 4; ++j) id[j] = nid[j];

    __syncthreads();   // protect As from next iteration's staging
  }

  // epilogue: C/D layout col = r16 (+j*16), row = quad*4 + r (+i*16)
#pragma unroll
  for (int j = 0; j < 4; ++j) {
    const int col = n0 + wn * 64 + j * 16 + r16;
#pragma unroll
    for (int i = 0; i < 8; ++i) {
      const int rbase = m0 + wm * 128 + i * 16 + quad * 4;
#pragma unroll
      for (int r = 0; r < 4; ++r)
        unsafeAtomicAdd(&out[(size_t)(rbase + r) * OUT_F + col], acc[i][j][r]);
    }
  }
}

extern "C" void kernel_launch(void* const* d_in, const int* in_sizes, int n_in,
                              void* d_out, int out_size, void* d_ws, size_t ws_size,
                              hipStream_t stream) {
  const float* x      = (const float*)d_in[0];  // [1024][4096] fp32
  const float* cent   = (const float*)d_in[1];  // [2048][8] fp32
  const float* bias   = (const float*)d_in[2];  // [4096] fp32
  const int*   assign = (const int*)d_in[3];    // [512*4096] int32
  float* out = (float*)d_out;

  // ws layout: xb (8 MB) | centb (32 KB)
  u16* xb    = (u16*)d_ws;
  u16* centb = (u16*)((char*)d_ws + (size_t)NTOK * IN_F * sizeof(u16));

  hipLaunchKernelGGL(prep_kernel, dim3((NTOK * IN_F / 8) / 256), dim3(256), 0, stream,
                     x, cent, bias, xb, centb, out);
  hipLaunchKernelGGL(gemm_fused4_kernel, dim3(OUT_F / BN, NTOK / BM, SPLITK), dim3(256), 0, stream,
                     xb, centb, assign, out);
}

// Round 6
// 162.690 us; speedup vs baseline: 1.0003x; 1.0003x over previous
//
#include <hip/hip_runtime.h>
#include <hip/hip_bf16.h>

#define IN_F   4096
#define OUT_F  4096
#define QBLK   8
#define NBLKS  512
#define NTOK   1024
#define NCENT  2048
#define SPLITK 4

typedef unsigned int u32;
typedef unsigned short u16;
typedef __attribute__((ext_vector_type(8))) short short8;   // 8 bf16 (MFMA A/B frag)
typedef __attribute__((ext_vector_type(4))) float floatx4;  // 16x16 MFMA C/D frag

// round-to-nearest-even fp32 -> bf16
__device__ __forceinline__ u16 f2bf(float f) {
  union { float f; u32 u; } v; v.f = f;
  u32 u = v.u;
  return (u16)((u + 0x7fffu + ((u >> 16) & 1u)) >> 16);
}

__device__ __forceinline__ void load_lds_16(const void* g, void* l) {
  __builtin_amdgcn_global_load_lds(
      (const __attribute__((address_space(1))) u32*)g,
      (__attribute__((address_space(3))) u32*)l, 16, 0, 0);
}

// ---------------------------------------------------------------------------
// Prep: cast x->bf16, cast centroids->bf16, init out = bias (for atomic GEMM).
// ---------------------------------------------------------------------------
__global__ __launch_bounds__(256) void prep_kernel(
    const float* __restrict__ x, const float* __restrict__ cent,
    const float* __restrict__ bias,
    u16* __restrict__ xb, u16* __restrict__ centb, float* __restrict__ out) {
  const int g = blockIdx.x * 256 + threadIdx.x;   // 0 .. 512K-1

  {
    const float4* xv = (const float4*)x;
    float4 a = xv[(size_t)g * 2];
    float4 b = xv[(size_t)g * 2 + 1];
    union { u16 s[8]; uint4 v; } o;
    o.s[0] = f2bf(a.x); o.s[1] = f2bf(a.y); o.s[2] = f2bf(a.z); o.s[3] = f2bf(a.w);
    o.s[4] = f2bf(b.x); o.s[5] = f2bf(b.y); o.s[6] = f2bf(b.z); o.s[7] = f2bf(b.w);
    ((uint4*)xb)[g] = o.v;
  }
  {
    const float4* b4 = (const float4*)bias;
    float4* o4 = (float4*)out;
    o4[(size_t)g * 2]     = b4[(2 * g) & 1023];
    o4[(size_t)g * 2 + 1] = b4[(2 * g + 1) & 1023];
  }
  if (g < NCENT) {
    const float4* cv = (const float4*)cent;
    float4 a = cv[(size_t)g * 2];
    float4 b = cv[(size_t)g * 2 + 1];
    union { u16 s[8]; uint4 v; } o;
    o.s[0] = f2bf(a.x); o.s[1] = f2bf(a.y); o.s[2] = f2bf(a.z); o.s[3] = f2bf(a.w);
    o.s[4] = f2bf(b.x); o.s[5] = f2bf(b.y); o.s[6] = f2bf(b.z); o.s[7] = f2bf(b.w);
    ((uint4*)centb)[g] = o.v;
  }
}

// ---------------------------------------------------------------------------
// Fused GEMM, double-buffered-A edition (round-2 skeleton + pipelining).
// C[m][n] += sum_k x[m][k] * centroids[assign[(k/8)*OUT_F+n]][k%8]
// Block 128x128, 4 waves (2x2), wave tile 64x64 = 4x4 of 16x16x32 MFMA.
// A: DMA-staged into As[2][128*32] (2x8KB). DMA for kt+1 issues at the TOP of
//    kt into the other buffer; ONE barrier per kt (end) both protects WAR and
//    drains a DMA that has had a full compute phase in flight. (Round 2
//    issued the DMA right before the draining barrier -> fully exposed
//    global->LDS latency every kt; that was the main stall.)
//    XOR swizzle chunk ^ ((row>>1)&3): each quad's 16 lanes spread over all
//    four 4-bank groups, 2 lanes each -> 2-way = free (m136).
// B: one 16B LDS gather per 16-col frag per 8-k quant block from the 32KB
//    bf16 centroid table; idx prefetched one kt ahead.
// Split-K=4 over gridDim.z; atomic accumulate into bias-pre-set out.
// ---------------------------------------------------------------------------
__global__ __launch_bounds__(256, 3) void gemm_fused5_kernel(
    const u16* __restrict__ A,      // xb [NTOK][IN_F] bf16
    const u16* __restrict__ centb,  // [NCENT][8] bf16
    const int* __restrict__ assign, // [NBLKS*OUT_F] block-major
    float* __restrict__ out) {      // [NTOK][OUT_F], pre-initialized to bias
  __shared__ __align__(16) u16 cs[NCENT * 8];     // 32 KB
  __shared__ __align__(16) u16 As[2][128 * 32];   // 2 x 8 KB
  const int NKT = (IN_F / SPLITK) / 32;           // 32 kt iterations

  const int t = threadIdx.x;
  const int lane = t & 63;
  const int wv = t >> 6;
  const int wm = wv >> 1;
  const int wn = wv & 1;
  const int quad = lane >> 4;
  const int r16 = lane & 15;
  const int m0 = blockIdx.y * 128;
  const int n0 = blockIdx.x * 128;
  const int k_base = blockIdx.z * (IN_F / SPLITK);

  // stage centroid table: 2048 x 16B chunks, 8 per thread (DMA)
#pragma unroll
  for (int it = 0; it < 8; ++it) {
    int c = it * 256 + t;
    load_lds_16(centb + (size_t)c * 8, cs + (size_t)c * 8);
  }

  // A staging: 512 chunks of 16B per tile, 2 per thread; chunk p -> row p>>2,
  // global-side swizzled chunk (p&3) ^ ((row>>1)&3)
  const int row0 = t >> 2;
  const u16* ag0 = A + (size_t)(m0 + row0) * IN_F + k_base + (((t & 3) ^ ((row0 >> 1) & 3)) * 8);
  const int row1 = (256 + t) >> 2;
  const u16* ag1 = A + (size_t)(m0 + row1) * IN_F + k_base + (((t & 3) ^ ((row1 >> 1) & 3)) * 8);

  // DMA As[0] for kt=0
  load_lds_16(ag0, &As[0][t * 8]);
  load_lds_16(ag1, &As[0][(256 + t) * 8]);

  floatx4 acc[4][4];
#pragma unroll
  for (int i = 0; i < 4; ++i)
#pragma unroll
    for (int j = 0; j < 4; ++j)
#pragma unroll
      for (int r = 0; r < 4; ++r) acc[i][j][r] = 0.0f;

  // idx: entry (kt, j) = ip[kt*4*OUT_F + j*16]; kb row = k_base/8 + kt*4 + quad
  const int* ip = assign + (size_t)((k_base >> 3) + quad) * OUT_F + n0 + wn * 64 + r16;
  int id[4];
#pragma unroll
  for (int j = 0; j < 4; ++j) id[j] = ip[j * 16];

  const short8* csv = (const short8*)cs;
  const int sq = quad ^ ((r16 >> 1) & 3);   // read-side swizzle (2-way free)
  const int abase = (wm * 64 + r16) * 4;    // x16B-chunk index of row r16, i=0

  __syncthreads();   // drains cs + As[0] DMA; all waves aligned

  for (int kt = 0; kt < NKT; ++kt) {
    const int cur = kt & 1;
    // issue DMA for kt+1 into the other buffer FIRST: a full compute phase
    // will elapse before the barrier that drains it.
    if (kt + 1 < NKT) {
      load_lds_16(ag0 + (kt + 1) * 32, &As[1 - cur][t * 8]);
      load_lds_16(ag1 + (kt + 1) * 32, &As[1 - cur][(256 + t) * 8]);
    }
    // prefetch idx for kt+1 (clamped re-read on last iter)
    const int ktn = (kt + 1 < NKT) ? (kt + 1) : kt;
    int nid[4];
#pragma unroll
    for (int j = 0; j < 4; ++j)
      nid[j] = ip[(size_t)(ktn * 4) * OUT_F + j * 16];

    // compute kt from As[cur]
    const short8* Asv = (const short8*)As[cur];
    short8 bfr[4];
#pragma unroll
    for (int j = 0; j < 4; ++j) bfr[j] = csv[id[j]];
    short8 af[4];
#pragma unroll
    for (int i = 0; i < 4; ++i)
      af[i] = Asv[abase + i * 64 + sq];   // row stride 16 rows * 4 chunks

#pragma unroll
    for (int i = 0; i < 4; ++i)
#pragma unroll
      for (int j = 0; j < 4; ++j)
        acc[i][j] = __builtin_amdgcn_mfma_f32_16x16x32_bf16(af[i], bfr[j], acc[i][j], 0, 0, 0);

#pragma unroll
    for (int j = 0; j < 4; ++j) id[j] = nid[j];

    __syncthreads();   // WAR-protect As[cur] + drain kt+1's DMA (in flight
                       // since loop top) before it becomes the read buffer
  }

  // epilogue: C/D layout col = r16 (+j*16), row = quad*4 + r (+i*16)
#pragma unroll
  for (int j = 0; j < 4; ++j) {
    const int col = n0 + wn * 64 + j * 16 + r16;
#pragma unroll
    for (int i = 0; i < 4; ++i) {
      const int rbase = m0 + wm * 64 + i * 16 + quad * 4;
#pragma unroll
      for (int r = 0; r < 4; ++r)
        unsafeAtomicAdd(&out[(size_t)(rbase + r) * OUT_F + col], acc[i][j][r]);
    }
  }
}

extern "C" void kernel_launch(void* const* d_in, const int* in_sizes, int n_in,
                              void* d_out, int out_size, void* d_ws, size_t ws_size,
                              hipStream_t stream) {
  const float* x      = (const float*)d_in[0];  // [1024][4096] fp32
  const float* cent   = (const float*)d_in[1];  // [2048][8] fp32
  const float* bias   = (const float*)d_in[2];  // [4096] fp32
  const int*   assign = (const int*)d_in[3];    // [512*4096] int32
  float* out = (float*)d_out;

  // ws layout: xb (8 MB) | centb (32 KB)
  u16* xb    = (u16*)d_ws;
  u16* centb = (u16*)((char*)d_ws + (size_t)NTOK * IN_F * sizeof(u16));

  hipLaunchKernelGGL(prep_kernel, dim3((NTOK * IN_F / 8) / 256), dim3(256), 0, stream,
                     x, cent, bias, xb, centb, out);
  hipLaunchKernelGGL(gemm_fused5_kernel, dim3(OUT_F / 128, NTOK / 128, SPLITK), dim3(256), 0, stream,
                     xb, centb, assign, out);
}

// Round 7
// 157.540 us; speedup vs baseline: 1.0330x; 1.0327x over previous
//
#include <hip/hip_runtime.h>
#include <hip/hip_bf16.h>

#define IN_F   4096
#define OUT_F  4096
#define QBLK   8
#define NBLKS  512
#define NTOK   1024
#define NCENT  2048
#define SPLITK 4

typedef unsigned int u32;
typedef unsigned short u16;
typedef __attribute__((ext_vector_type(8))) short short8;   // 8 bf16 (MFMA A/B frag)
typedef __attribute__((ext_vector_type(4))) float floatx4;  // 16x16 MFMA C/D frag

// round-to-nearest-even fp32 -> bf16
__device__ __forceinline__ u16 f2bf(float f) {
  union { float f; u32 u; } v; v.f = f;
  u32 u = v.u;
  return (u16)((u + 0x7fffu + ((u >> 16) & 1u)) >> 16);
}

__device__ __forceinline__ void load_lds_16(const void* g, void* l) {
  __builtin_amdgcn_global_load_lds(
      (const __attribute__((address_space(1))) u32*)g,
      (__attribute__((address_space(3))) u32*)l, 16, 0, 0);
}

// ---------------------------------------------------------------------------
// Prep: cast x->bf16, cast centroids->bf16, init out = bias (for atomic GEMM).
// ---------------------------------------------------------------------------
__global__ __launch_bounds__(256) void prep_kernel(
    const float* __restrict__ x, const float* __restrict__ cent,
    const float* __restrict__ bias,
    u16* __restrict__ xb, u16* __restrict__ centb, float* __restrict__ out) {
  const int g = blockIdx.x * 256 + threadIdx.x;   // 0 .. 512K-1

  {
    const float4* xv = (const float4*)x;
    float4 a = xv[(size_t)g * 2];
    float4 b = xv[(size_t)g * 2 + 1];
    union { u16 s[8]; uint4 v; } o;
    o.s[0] = f2bf(a.x); o.s[1] = f2bf(a.y); o.s[2] = f2bf(a.z); o.s[3] = f2bf(a.w);
    o.s[4] = f2bf(b.x); o.s[5] = f2bf(b.y); o.s[6] = f2bf(b.z); o.s[7] = f2bf(b.w);
    ((uint4*)xb)[g] = o.v;
  }
  {
    const float4* b4 = (const float4*)bias;
    float4* o4 = (float4*)out;
    o4[(size_t)g * 2]     = b4[(2 * g) & 1023];
    o4[(size_t)g * 2 + 1] = b4[(2 * g + 1) & 1023];
  }
  if (g < NCENT) {
    const float4* cv = (const float4*)cent;
    float4 a = cv[(size_t)g * 2];
    float4 b = cv[(size_t)g * 2 + 1];
    union { u16 s[8]; uint4 v; } o;
    o.s[0] = f2bf(a.x); o.s[1] = f2bf(a.y); o.s[2] = f2bf(a.z); o.s[3] = f2bf(a.w);
    o.s[4] = f2bf(b.x); o.s[5] = f2bf(b.y); o.s[6] = f2bf(b.z); o.s[7] = f2bf(b.w);
    ((uint4*)centb)[g] = o.v;
  }
}

// ---------------------------------------------------------------------------
// Fused GEMM — round-2 skeleton (the best measured structure: 51 µs) with
// surgical fixes only.
// C[m][n] += sum_k x[m][k] * centroids[assign[(k/8)*OUT_F+n]][k%8]
// Block 128x128, 4 waves (2x2), wave tile 64x64 = 4x4 of 16x16x32 MFMA
// (16 independent accumulators -> deep MFMA pipelining; 32x32 variant's
// chained accs measured 2x slower).
// A: DMA-staged single 8KB buffer per BK=32. Two barriers per kt, DMA issued
//    just before barrier1 — relies on 4 resident blocks/CU for overlap
//    (measured: explicit dbuf at 3 blocks/CU is 2x WORSE — occupancy is the
//    latency-hiding mechanism here, not intra-block pipelining).
//    XOR swizzle chunk ^ ((row>>1)&3): quad's 16 lanes spread over all four
//    4-bank groups, 2 lanes each -> 2-way = free (m136; verified -2.1M
//    conflicts in round 6).
// B: one 16B LDS gather per 16-col frag per 8-k quant block from the 32KB
//    bf16 centroid table (the dequant, fused — cheaper than any
//    materialize-W variant measured).
// LDS total 40KB -> 4 blocks/CU. Split-K=4; atomic accumulate into
// bias-pre-set out (kills the reduce kernel + 48MB partials traffic).
// ---------------------------------------------------------------------------
__global__ __launch_bounds__(256, 4) void gemm_fused7_kernel(
    const u16* __restrict__ A,      // xb [NTOK][IN_F] bf16
    const u16* __restrict__ centb,  // [NCENT][8] bf16
    const int* __restrict__ assign, // [NBLKS*OUT_F] block-major
    float* __restrict__ out) {      // [NTOK][OUT_F], pre-initialized to bias
  __shared__ __align__(16) u16 cs[NCENT * 8];   // 32 KB
  __shared__ __align__(16) u16 As[128 * 32];    // 8 KB
  const int NKT = (IN_F / SPLITK) / 32;         // 32 kt iterations

  const int t = threadIdx.x;
  const int lane = t & 63;
  const int wv = t >> 6;
  const int wm = wv >> 1;
  const int wn = wv & 1;
  const int quad = lane >> 4;
  const int r16 = lane & 15;
  const int m0 = blockIdx.y * 128;
  const int n0 = blockIdx.x * 128;
  const int k_base = blockIdx.z * (IN_F / SPLITK);

  // stage centroid table: 2048 x 16B chunks, 8 per thread (DMA)
#pragma unroll
  for (int it = 0; it < 8; ++it) {
    int c = it * 256 + t;
    load_lds_16(centb + (size_t)c * 8, cs + (size_t)c * 8);
  }

  floatx4 acc[4][4];
#pragma unroll
  for (int i = 0; i < 4; ++i)
#pragma unroll
    for (int j = 0; j < 4; ++j)
#pragma unroll
      for (int r = 0; r < 4; ++r) acc[i][j][r] = 0.0f;

  // idx: entry (kt, j) = ip[kt*4*OUT_F + j*16]; kb row = k_base/8 + kt*4 + quad
  const int* ip = assign + (size_t)((k_base >> 3) + quad) * OUT_F + n0 + wn * 64 + r16;

  // A staging: 512 chunks of 16B per tile, 2 per thread; chunk p -> row p>>2,
  // global-side swizzled chunk (p&3) ^ ((row>>1)&3)
  const int row0 = t >> 2;
  const u16* ag0 = A + (size_t)(m0 + row0) * IN_F + k_base + (((t & 3) ^ ((row0 >> 1) & 3)) * 8);
  const int row1 = (256 + t) >> 2;
  const u16* ag1 = A + (size_t)(m0 + row1) * IN_F + k_base + (((t & 3) ^ ((row1 >> 1) & 3)) * 8);

  const short8* csv = (const short8*)cs;
  const short8* Asv = (const short8*)As;
  const int sq = quad ^ ((r16 >> 1) & 3);   // read-side swizzle (2-way free)
  const int abase = (wm * 64 + r16) * 4;    // 16B-chunk index of row r16, i=0

  for (int kt = 0; kt < NKT; ++kt) {
    // idx loads for THIS kt: issued before the DMA+barrier so their global
    // latency overlaps the drain (consumed only after barrier1)
    int id[4];
#pragma unroll
    for (int j = 0; j < 4; ++j)
      id[j] = ip[(size_t)(kt * 4) * OUT_F + j * 16];

    // stage A tile for this kt (2 DMA chunks per thread)
    load_lds_16(ag0 + kt * 32, &As[t * 8]);
    load_lds_16(ag1 + kt * 32, &As[(256 + t) * 8]);
    __syncthreads();   // barrier1: drains DMA (incl. cs on kt=0) + idx loads

    short8 bfr[4];
#pragma unroll
    for (int j = 0; j < 4; ++j) bfr[j] = csv[id[j]];
    short8 af[4];
#pragma unroll
    for (int i = 0; i < 4; ++i)
      af[i] = Asv[abase + i * 64 + sq];   // row stride 16 rows * 4 chunks

#pragma unroll
    for (int i = 0; i < 4; ++i)
#pragma unroll
      for (int j = 0; j < 4; ++j)
        acc[i][j] = __builtin_amdgcn_mfma_f32_16x16x32_bf16(af[i], bfr[j], acc[i][j], 0, 0, 0);

    __syncthreads();   // barrier2: protect As from next iteration's staging
  }

  // epilogue: C/D layout col = r16 (+j*16), row = quad*4 + r (+i*16)
#pragma unroll
  for (int j = 0; j < 4; ++j) {
    const int col = n0 + wn * 64 + j * 16 + r16;
#pragma unroll
    for (int i = 0; i < 4; ++i) {
      const int rbase = m0 + wm * 64 + i * 16 + quad * 4;
#pragma unroll
      for (int r = 0; r < 4; ++r)
        unsafeAtomicAdd(&out[(size_t)(rbase + r) * OUT_F + col], acc[i][j][r]);
    }
  }
}

extern "C" void kernel_launch(void* const* d_in, const int* in_sizes, int n_in,
                              void* d_out, int out_size, void* d_ws, size_t ws_size,
                              hipStream_t stream) {
  const float* x      = (const float*)d_in[0];  // [1024][4096] fp32
  const float* cent   = (const float*)d_in[1];  // [2048][8] fp32
  const float* bias   = (const float*)d_in[2];  // [4096] fp32
  const int*   assign = (const int*)d_in[3];    // [512*4096] int32
  float* out = (float*)d_out;

  // ws layout: xb (8 MB) | centb (32 KB)
  u16* xb    = (u16*)d_ws;
  u16* centb = (u16*)((char*)d_ws + (size_t)NTOK * IN_F * sizeof(u16));

  hipLaunchKernelGGL(prep_kernel, dim3((NTOK * IN_F / 8) / 256), dim3(256), 0, stream,
                     x, cent, bias, xb, centb, out);
  hipLaunchKernelGGL(gemm_fused7_kernel, dim3(OUT_F / 128, NTOK / 128, SPLITK), dim3(256), 0, stream,
                     xb, centb, assign, out);
}